// Round 8
// baseline (63.735 us; speedup 1.0000x reference)
//
#include <hip/hip_runtime.h>
#include <stdint.h>

// YOLOv3 head decode: B=32, NA=3 anchors, 76x76 grid, 85 attrs, stride=8.
// in : [B, 255, 76, 76] f32   (c-major, spatial contiguous)
// out: [B, 3*76*76, 85] f32   (attr contiguous)
//
// Two rows per block, double-buffered pipeline (A=row0, B=row1):
//   stage(A); bar; stage(B)+xform(A); bar; scatter(A)+xform(B); bar;
//   store(A)+scatter(B); bar; store(B)
// All LDS patterns conflict-free (R7-verified):
//   xform read : slot cc*19+gxq, lane stride 76 dw == 12 mod 32 -> banks tile
//   scatter    : consecutive lane addresses
//   store read : contiguous b128

#define GH 76
#define GW 76
#define NA 3
#define ATTRS 85
#define SPATIAL (GH * GW)          // 5776
#define NCHUNK 1615                // 85 * 19 = 76*85/4
#define ROWF (GW * ATTRS)          // 6460 floats per output row
#define LOG2E 1.4426950408889634f

typedef float f32x4 __attribute__((ext_vector_type(4)));
typedef const __attribute__((address_space(1))) uint32_t gu32;
typedef __attribute__((address_space(3))) uint32_t lu32;

__global__ __launch_bounds__(512) void yolo_head_kernel(
    const float* __restrict__ in, float* __restrict__ out, int nwg2) {
    // ---- bijective XCD swizzle over block-pairs ----
    const int L = blockIdx.x;
    const int q = nwg2 >> 3, r = nwg2 & 7, xcd = L & 7;
    const int Wp = (xcd < r ? xcd * (q + 1) : r * (q + 1) + (xcd - r) * q) + (L >> 3);
    const int row0 = Wp * 2;           // row = (b*NA + a)*GH + gy

    __shared__ float tile[2][NCHUNK * 4];   // 2 x 25840 B

    const int tid = threadIdx.x;

    // per-thread chunk coords (row-independent)
    int gxq_[4], cc_[4];
#pragma unroll
    for (int k = 0; k < 4; ++k) {
        const int m = tid + k * 512;
        const int gxq = m / 85;
        gxq_[k] = gxq;
        cc_[k]  = m - gxq * 85;
    }

    auto stage = [&](float* buf, int row) {
        const int gy = row % GH, t = row / GH, a = t % NA, b = t / NA;
        const float* inb = in + ((size_t)(b * (NA * ATTRS) + a * ATTRS)) * SPATIAL
                              + (size_t)gy * GW;
#pragma unroll
        for (int k = 0; k < 4; ++k) {
            const int s = tid + k * 512;
            if (s < NCHUNK) {
                const int c   = s / 19;
                const int gcx = s - c * 19;
                const float* src = inb + (size_t)c * SPATIAL + (gcx << 2);
                __builtin_amdgcn_global_load_lds((gu32*)src, (lu32*)&buf[s << 2], 16, 0, 0);
            }
        }
    };

    auto xform = [&](const float* buf, int row, f32x4* res) {
        const int gy = row % GH, t2 = row / GH, a = t2 % NA;
        const float aw = (a == 0) ? 10.0f : (a == 1) ? 16.0f : 33.0f;
        const float ah = (a == 0) ? 13.0f : (a == 1) ? 30.0f : 23.0f;
#pragma unroll
        for (int k = 0; k < 4; ++k) {
            const int m = tid + k * 512;
            if (m < NCHUNK) {
                const int gxq = gxq_[k], cc = cc_[k];
                const f32x4 v = *reinterpret_cast<const f32x4*>(&buf[(cc * 19 + gxq) << 2]);
                f32x4 E, rs;
#pragma unroll
                for (int t = 0; t < 4; ++t) {
                    E[t]  = __builtin_amdgcn_exp2f(LOG2E * v[t]);        // e^x
                    rs[t] = E[t] * __builtin_amdgcn_rcpf(1.0f + E[t]);   // sigmoid
                }
                if (cc < 4) {
                    const float gx0 = (float)(gxq << 2);
#pragma unroll
                    for (int t = 0; t < 4; ++t) {
                        if      (cc == 0) rs[t] = (rs[t] + gx0 + (float)t) * 8.0f;
                        else if (cc == 1) rs[t] = (rs[t] + (float)gy) * 8.0f;
                        else if (cc == 2) rs[t] = E[t] * aw;
                        else              rs[t] = E[t] * ah;
                    }
                }
                res[k] = rs;
            }
        }
    };

    auto scatter = [&](float* buf, const f32x4* res) {
#pragma unroll
        for (int k = 0; k < 4; ++k) {
            const int m = tid + k * 512;
            if (m < NCHUNK) {
                const int base = (gxq_[k] << 2) * ATTRS + cc_[k];
#pragma unroll
                for (int t = 0; t < 4; ++t)
                    buf[base + t * ATTRS] = res[k][t];
            }
        }
    };

    auto storeRow = [&](const float* buf, int row) {
        float* outb = out + (size_t)row * ROWF;
#pragma unroll
        for (int k = 0; k < 4; ++k) {
            const int m = tid + k * 512;
            if (m < NCHUNK) {
                const f32x4 v = *reinterpret_cast<const f32x4*>(&buf[m << 2]);
                __builtin_nontemporal_store(v, reinterpret_cast<f32x4*>(outb + (m << 2)));
            }
        }
    };

    f32x4 res0[4], res1[4];

    stage(tile[0], row0);
    __syncthreads();                       // stage(A) done

    stage(tile[1], row0 + 1);              // B's HBM latency hides under xform(A)
    xform(tile[0], row0, res0);
    __syncthreads();                       // drains stage(B) + xform(A) reads

    scatter(tile[0], res0);
    xform(tile[1], row0 + 1, res1);
    __syncthreads();                       // scatter(A) visible; xform(B) reads done

    storeRow(tile[0], row0);               // store stream overlaps B's LDS writes
    scatter(tile[1], res1);
    __syncthreads();                       // scatter(B) visible

    storeRow(tile[1], row0 + 1);
}

extern "C" void kernel_launch(void* const* d_in, const int* in_sizes, int n_in,
                              void* d_out, int out_size, void* d_ws, size_t ws_size,
                              hipStream_t stream) {
    const float* in = (const float*)d_in[0];
    float* out = (float*)d_out;
    const int B = in_sizes[0] / (NA * ATTRS * SPATIAL);  // 32
    const int nwg2 = GH * NA * B / 2;                    // 3648 block-pairs (228*B always even)
    yolo_head_kernel<<<dim3(nwg2), 512, 0, stream>>>(in, out, nwg2);
}

// Round 9
// 57.098 us; speedup vs baseline: 1.1162x; 1.1162x over previous
//
#include <hip/hip_runtime.h>
#include <stdint.h>

// YOLOv3 head decode: B=32, NA=3 anchors, 76x76 grid, 85 attrs, stride=8.
// in : [B, 255, 76, 76] f32   (c-major, spatial contiguous)
// out: [B, 3*76*76, 85] f32   (attr contiguous)
//
// BARRIER-FREE wave-autonomous transpose. Unit = (row, 4-column group):
//   stage  : 85 x global_load_lds 16B (channel c -> staged[c]), linear LDS
//   wait   : s_waitcnt vmcnt(0)        (wave-local, no __syncthreads)
//   xform  : ds_read_b128 staged[c] (contiguous), transform in regs,
//            scatter outbuf[t*85+c] (lanes consecutive: 2/bank = free)
//   wait   : s_waitcnt lgkmcnt(0)      (wave-local)
//   store  : contiguous NT dwordx4 (group = 1360 B, 16B-aligned)
// 2.72 KB LDS per wave -> 10.9 KB per 256-thr block -> 8 blocks/CU = 32 waves.

#define GH 76
#define GW 76
#define NA 3
#define ATTRS 85
#define SPATIAL (GH * GW)          // 5776
#define NGRP 19                    // 76/4 column groups per row
#define LOG2E 1.4426950408889634f

typedef float f32x4 __attribute__((ext_vector_type(4)));
typedef const __attribute__((address_space(1))) uint32_t gu32;
typedef __attribute__((address_space(3))) uint32_t lu32;

__global__ __launch_bounds__(256) void yolo_head_kernel(
    const float* __restrict__ in, float* __restrict__ out, int nwg) {
    // ---- bijective XCD swizzle (nwg % 8 == 0 here) ----
    const int L = blockIdx.x;
    const int q = nwg >> 3, r = nwg & 7, xcd = L & 7;
    const int W = (xcd < r ? xcd * (q + 1) : r * (q + 1) + (xcd - r) * q) + (L >> 3);

    const int lane = threadIdx.x & 63;
    const int wv   = threadIdx.x >> 6;

    const int u   = W * 4 + wv;        // unit = (row, group); consecutive units same XCD
    const int row = u / NGRP;          // row = (b*NA + a)*GH + gy
    const int g   = u - row * NGRP;    // column group, gx = g*4 .. g*4+3
    const int gy  = row % GH;
    const int t2  = row / GH;
    const int a   = t2 % NA;
    const int b   = t2 / NA;

    const float aw = (a == 0) ? 10.0f : (a == 1) ? 16.0f : 33.0f;
    const float ah = (a == 0) ? 13.0f : (a == 1) ? 30.0f : 23.0f;

    __shared__ float lds[4][2 * ATTRS * 4];     // per wave: staged[340] + outbuf[340]
    float* staged = lds[wv];
    float* outbuf = lds[wv] + ATTRS * 4;

    const float* inb = in + ((size_t)(b * (NA * ATTRS) + a * ATTRS)) * SPATIAL
                          + (size_t)gy * GW + g * 4;

    // ---- stage: one 16B chunk per channel, DMA direct to LDS (linear) ----
#pragma unroll
    for (int k = 0; k < 2; ++k) {
        const int c = lane + k * 64;
        if (c < ATTRS)
            __builtin_amdgcn_global_load_lds((gu32*)(inb + (size_t)c * SPATIAL),
                                             (lu32*)&staged[c * 4], 16, 0, 0);
    }
    asm volatile("s_waitcnt vmcnt(0)" ::: "memory");   // wave-local wait

    // ---- transform + scatter (channel uniform per lane) ----
#pragma unroll
    for (int k = 0; k < 2; ++k) {
        const int c = lane + k * 64;
        if (c < ATTRS) {
            const f32x4 v = *reinterpret_cast<const f32x4*>(&staged[c * 4]);
            f32x4 E, rs;
#pragma unroll
            for (int t = 0; t < 4; ++t) {
                E[t]  = __builtin_amdgcn_exp2f(LOG2E * v[t]);        // e^x
                rs[t] = E[t] * __builtin_amdgcn_rcpf(1.0f + E[t]);   // sigmoid
            }
            if (c < 4) {
                const float gx0 = (float)(g * 4);
#pragma unroll
                for (int t = 0; t < 4; ++t) {
                    if      (c == 0) rs[t] = (rs[t] + gx0 + (float)t) * 8.0f;
                    else if (c == 1) rs[t] = (rs[t] + (float)gy) * 8.0f;
                    else if (c == 2) rs[t] = E[t] * aw;
                    else              rs[t] = E[t] * ah;
                }
            }
#pragma unroll
            for (int t = 0; t < 4; ++t)
                outbuf[t * ATTRS + c] = rs[t];   // lanes consecutive: 2/bank, free
        }
    }
    asm volatile("s_waitcnt lgkmcnt(0)" ::: "memory");  // wave-local wait

    // ---- store: contiguous NT dwordx4 stream ----
    float* outg = out + (size_t)row * (GW * ATTRS) + g * (4 * ATTRS);
#pragma unroll
    for (int k = 0; k < 2; ++k) {
        const int j = lane + k * 64;
        if (j < ATTRS) {
            const f32x4 v = *reinterpret_cast<const f32x4*>(&outbuf[j * 4]);
            __builtin_nontemporal_store(v, reinterpret_cast<f32x4*>(outg + j * 4));
        }
    }
}

extern "C" void kernel_launch(void* const* d_in, const int* in_sizes, int n_in,
                              void* d_out, int out_size, void* d_ws, size_t ws_size,
                              hipStream_t stream) {
    const float* in = (const float*)d_in[0];
    float* out = (float*)d_out;
    const int B = in_sizes[0] / (NA * ATTRS * SPATIAL);  // 32
    const int nunits = GH * NA * B * NGRP;               // 138624
    const int nwg = nunits / 4;                          // 34656 (div by 8)
    yolo_head_kernel<<<dim3(nwg), 256, 0, stream>>>(in, out, nwg);
}